// Round 3
// baseline (728.627 us; speedup 1.0000x reference)
//
#include <hip/hip_runtime.h>
#include <math.h>

// Round 3: two-level LDS-staged binning — every global store coalesced.
// dur breakdown discovered: 172us of dur is the harness poisoning the 1 GiB d_ws
// (present whether or not we use ws) -> use ws freely.
// Random 8B global stores run at ~1.2 TB/s effective (64B partial-line RMW);
// replace them with LDS bucket staging + contiguous burst flushes.
//
//  P1: pairs -> 64 groups (128 rows).  LDS stage 64 x 112 entries, burst flush.
//  P2: group entries -> 32 subgroups (4 rows) each. LDS stage 32 x 128, burst flush.
//  P3: per 4-row subgroup: zero 128KiB LDS -> scatter entries (key&32767 indexes
//      LDS directly) -> diag -> stream 128KiB contiguous float4 to out.
//
// entry = uint2 { key = (row<<13)|col , f32 bits of val*scale }
// group = row>>7 = key>>20 ; subgroup-in-group = (key>>15)&31 ; lds idx = key&32767.

#define P1_PAIRS 2048
#define P1_CAP   112
#define NGRP     64
#define CAP1     65536
#define SUBG     32
#define NSUB     2048
#define CAP2     2048
#define P2_CAP   128
#define P2_BPG   32       // blocks per group in phase 2

// ---------------------------------------------------------------- new path

__global__ __launch_bounds__(256) void zero_cursors_kernel(int* __restrict__ gcur1,
                                                           int* __restrict__ gcur2)
{
    int t = blockIdx.x * blockDim.x + threadIdx.x;
    if (t < NGRP) gcur1[t] = 0;
    if (t < NSUB) gcur2[t] = 0;
}

__global__ __launch_bounds__(256) void p1_bin_kernel(
    const int*   __restrict__ idx,     // [2, M]
    const float* __restrict__ vals,    // [M]
    float scale,
    int m,
    uint2* __restrict__ region1,       // [NGRP, CAP1]
    int*   __restrict__ gcur1)         // [NGRP]
{
    __shared__ uint2 stage[NGRP][P1_CAP];   // 56 KiB
    __shared__ int   cnt[NGRP];

    for (int b = threadIdx.x; b < NGRP; b += blockDim.x) cnt[b] = 0;
    __syncthreads();

    const int base = blockIdx.x * P1_PAIRS;
    for (int t = threadIdx.x; t < P1_PAIRS; t += blockDim.x) {
        int k = base + t;
        if (k >= m) break;                       // k strictly increases
        int i = idx[k];
        int j = idx[m + k];
        unsigned vb = __float_as_uint(vals[k] * scale);

        unsigned key1 = ((unsigned)i << 13) | (unsigned)j;
        int b1 = i >> 7;
        int p1 = atomicAdd(&cnt[b1], 1);
        if (p1 < P1_CAP) stage[b1][p1] = make_uint2(key1, vb);
        else {
            int s = atomicAdd(&gcur1[b1], 1);
            if (s < CAP1) region1[(long long)b1 * CAP1 + s] = make_uint2(key1, vb);
        }

        unsigned key2 = ((unsigned)j << 13) | (unsigned)i;
        int b2 = j >> 7;
        int p2 = atomicAdd(&cnt[b2], 1);
        if (p2 < P1_CAP) stage[b2][p2] = make_uint2(key2, vb);
        else {
            int s = atomicAdd(&gcur1[b2], 1);
            if (s < CAP1) region1[(long long)b2 * CAP1 + s] = make_uint2(key2, vb);
        }
    }
    __syncthreads();

    // burst-flush each bucket: one wave per bucket at a time
    const int wave = threadIdx.x >> 6;
    const int lane = threadIdx.x & 63;
    const int nw   = blockDim.x >> 6;
    for (int b = wave; b < NGRP; b += nw) {
        int c = cnt[b]; if (c > P1_CAP) c = P1_CAP;
        int bs = 0;
        if (lane == 0) bs = atomicAdd(&gcur1[b], c);
        bs = __shfl(bs, 0);
        for (int e = lane; e < c; e += 64) {
            int s = bs + e;
            if (s < CAP1) region1[(long long)b * CAP1 + s] = stage[b][e];
        }
    }
}

__global__ __launch_bounds__(256) void p2_bin_kernel(
    const uint2* __restrict__ region1,
    const int*   __restrict__ gcur1,
    uint2* __restrict__ region2,       // [NSUB, CAP2]
    int*   __restrict__ gcur2)         // [NSUB]
{
    __shared__ uint2 stage[SUBG][P2_CAP];   // 32 KiB
    __shared__ int   cnt[SUBG];

    const int g  = blockIdx.x / P2_BPG;
    const int tb = blockIdx.x % P2_BPG;

    int n1 = gcur1[g]; if (n1 > CAP1) n1 = CAP1;
    int per = (n1 + P2_BPG - 1) / P2_BPG;
    int s0 = tb * per;
    int s1 = s0 + per; if (s1 > n1) s1 = n1;

    for (int b = threadIdx.x; b < SUBG; b += blockDim.x) cnt[b] = 0;
    __syncthreads();

    for (int e = s0 + threadIdx.x; e < s1; e += blockDim.x) {
        uint2 en = region1[(long long)g * CAP1 + e];
        int b = (en.x >> 15) & 31;
        int p = atomicAdd(&cnt[b], 1);
        if (p < P2_CAP) stage[b][p] = en;
        else {
            int sg = g * SUBG + b;
            int s = atomicAdd(&gcur2[sg], 1);
            if (s < CAP2) region2[(long long)sg * CAP2 + s] = en;
        }
    }
    __syncthreads();

    const int wave = threadIdx.x >> 6;
    const int lane = threadIdx.x & 63;
    const int nw   = blockDim.x >> 6;
    for (int b = wave; b < SUBG; b += nw) {
        int c = cnt[b]; if (c > P2_CAP) c = P2_CAP;
        int sg = g * SUBG + b;
        int bs = 0;
        if (lane == 0) bs = atomicAdd(&gcur2[sg], c);
        bs = __shfl(bs, 0);
        for (int e = lane; e < c; e += 64) {
            int s = bs + e;
            if (s < CAP2) region2[(long long)sg * CAP2 + s] = stage[b][e];
        }
    }
}

__global__ __launch_bounds__(512) void p3_rows_kernel(
    float* __restrict__ out,
    const float* __restrict__ h_local,
    const uint2* __restrict__ region2,
    const int*   __restrict__ gcur2)
{
    __shared__ float srow[4 * 8192];               // 128 KiB: 4 full rows
    const int s  = blockIdx.x;                     // subgroup id
    const int r0 = s << 2;
    float4* s4 = reinterpret_cast<float4*>(srow);

    for (int c = threadIdx.x; c < 8192; c += blockDim.x)
        s4[c] = make_float4(0.f, 0.f, 0.f, 0.f);
    __syncthreads();

    int n = gcur2[s]; if (n > CAP2) n = CAP2;
    const uint2* eb = region2 + (long long)s * CAP2;
    for (int e = threadIdx.x; e < n; e += blockDim.x) {
        uint2 en = eb[e];
        srow[en.x & 32767] = __uint_as_float(en.y); // (row&3)<<13 | col
    }
    if (threadIdx.x < 4) {
        int r = r0 + threadIdx.x;
        srow[(threadIdx.x << 13) | r] = h_local[r];
    }
    __syncthreads();

    float4* orow = reinterpret_cast<float4*>(out + ((long long)r0 << 13));
    for (int c = threadIdx.x; c < 8192; c += blockDim.x)
        orow[c] = s4[c];
}

// ---------------------------------------------------------------- round-2 fallback

__global__ __launch_bounds__(256) void init_counts_kernel(
    float* __restrict__ out, int d, int logd)
{
    int r = blockIdx.x * blockDim.x + threadIdx.x;
    if (r < d) reinterpret_cast<int*>(out)[(long long)r << logd] = 0;
}

__global__ __launch_bounds__(256) void bin_kernel(
    float* __restrict__ out,
    const int*   __restrict__ idx,
    const float* __restrict__ vals,
    float scale, int m, int logd, int cap)
{
    int k = blockIdx.x * blockDim.x + threadIdx.x;
    if (k >= m) return;
    int i = idx[k];
    int j = idx[m + k];
    unsigned vb = __float_as_uint(vals[k] * scale);

    int* cnt_i = reinterpret_cast<int*>(out) + ((long long)i << logd);
    int* cnt_j = reinterpret_cast<int*>(out) + ((long long)j << logd);

    int p1 = atomicAdd(cnt_i, 1);
    if (p1 < cap)
        *reinterpret_cast<uint2*>(out + ((long long)i << logd) + 2 + 2 * p1) =
            make_uint2((unsigned)j, vb);
    int p2 = atomicAdd(cnt_j, 1);
    if (p2 < cap)
        *reinterpret_cast<uint2*>(out + ((long long)j << logd) + 2 + 2 * p2) =
            make_uint2((unsigned)i, vb);
}

__global__ __launch_bounds__(256) void rows_kernel(
    float* __restrict__ out,
    const float* __restrict__ h_local,
    int logd, int cap)
{
    __shared__ float srow[8192];
    const int d  = 1 << logd;
    const int n4 = d >> 2;
    float4* s4 = reinterpret_cast<float4*>(srow);

    const int r = blockIdx.x;
    float* grow = out + ((long long)r << logd);

    const float4 z = make_float4(0.f, 0.f, 0.f, 0.f);
    for (int c = threadIdx.x; c < n4; c += blockDim.x) s4[c] = z;
    __syncthreads();

    int cnt = reinterpret_cast<const int*>(grow)[0];
    if (cnt > cap) cnt = cap;
    const uint2* eb = reinterpret_cast<const uint2*>(grow + 2);
    for (int e = threadIdx.x; e < cnt; e += blockDim.x) {
        uint2 p = eb[e];
        srow[p.x] = __uint_as_float(p.y);
    }
    if (threadIdx.x == 0) srow[r] = h_local[r];
    __syncthreads();

    for (int c = threadIdx.x; c < n4; c += blockDim.x)
        reinterpret_cast<float4*>(grow)[c] = s4[c];
}

// ---------------------------------------------------------------- naive fallback

__global__ __launch_bounds__(256) void fill_diag_kernel(
    float* __restrict__ out, const float* __restrict__ h_local,
    int d, long long n)
{
    long long t = (long long)blockIdx.x * blockDim.x + threadIdx.x;
    if (t >= n) return;
    long long row = t / d;
    long long col = t - row * d;
    out[t] = (row == col) ? h_local[row] : 0.f;
}

__global__ __launch_bounds__(256) void scatter_kernel(
    float* __restrict__ out,
    const int* __restrict__ idx,
    const float* __restrict__ vals,
    float scale, int m, int d)
{
    int k = blockIdx.x * blockDim.x + threadIdx.x;
    if (k >= m) return;
    int i = idx[k];
    int j = idx[m + k];
    float v = vals[k] * scale;
    out[(long long)i * d + j] = v;
    out[(long long)j * d + i] = v;
}

// ---------------------------------------------------------------- launch

extern "C" void kernel_launch(void* const* d_in, const int* in_sizes, int n_in,
                              void* d_out, int out_size, void* d_ws, size_t ws_size,
                              hipStream_t stream) {
    const float* h_local = (const float*)d_in[0];
    const float* V_int   = (const float*)d_in[1];
    const int*   idx     = (const int*)d_in[2];

    const int d = in_sizes[0];            // 8192
    const int m = in_sizes[1];            // 1,600,000

    int logd = 0;
    while ((1 << logd) < d) ++logd;
    const bool pow2 = ((1 << logd) == d);

    const float iscale = (float)(1.0 - 0.2 / sqrt(log((double)d)));
    float* out = (float*)d_out;
    const int block = 256;

    // ws layout: [gcur1: 64 int][pad][gcur2: 2048 int][pad to 16KB]
    //            [region1: NGRP*CAP1*8B = 32MB][region2: NSUB*CAP2*8B = 32MB]
    const size_t off_cur2 = 4096;
    const size_t off_r1   = 16384;
    const size_t off_r2   = off_r1 + (size_t)NGRP * CAP1 * sizeof(uint2);
    const size_t ws_need  = off_r2 + (size_t)NSUB * CAP2 * sizeof(uint2);

    const bool path3 = (d == 8192) && (m > 0) && (m <= 1800000) &&
                       (d_ws != nullptr) && (ws_size >= ws_need);

    if (path3) {
        int*   gcur1   = (int*)d_ws;
        int*   gcur2   = (int*)((char*)d_ws + off_cur2);
        uint2* region1 = (uint2*)((char*)d_ws + off_r1);
        uint2* region2 = (uint2*)((char*)d_ws + off_r2);

        zero_cursors_kernel<<<(NSUB + block - 1) / block, block, 0, stream>>>(gcur1, gcur2);

        const int grid1 = (m + P1_PAIRS - 1) / P1_PAIRS;      // 782
        p1_bin_kernel<<<grid1, block, 0, stream>>>(idx, V_int, iscale, m, region1, gcur1);

        p2_bin_kernel<<<NGRP * P2_BPG, block, 0, stream>>>(region1, gcur1, region2, gcur2);

        p3_rows_kernel<<<NSUB, 512, 0, stream>>>(out, h_local, region2, gcur2);
    } else if (pow2 && d >= 1024 && d <= 8192 &&
               ((long long)m * 2 / d) < (long long)((d - 2) / 2) / 2) {
        const int cap = (d - 2) / 2;
        init_counts_kernel<<<(d + block - 1) / block, block, 0, stream>>>(out, d, logd);
        bin_kernel<<<(m + block - 1) / block, block, 0, stream>>>(out, idx, V_int,
                                                                  iscale, m, logd, cap);
        rows_kernel<<<d, block, 0, stream>>>(out, h_local, logd, cap);
    } else {
        const long long n = (long long)d * d;
        const long long grid_fill = (n + block - 1) / block;
        fill_diag_kernel<<<(dim3)(unsigned)grid_fill, block, 0, stream>>>(out, h_local, d, n);
        const int grid_sc = (m + block - 1) / block;
        scatter_kernel<<<grid_sc, block, 0, stream>>>(out, idx, V_int, iscale, m, d);
    }
}

// Round 4
// 388.296 us; speedup vs baseline: 1.8765x; 1.8765x over previous
//
#include <hip/hip_runtime.h>
#include <math.h>

// Round 4: atomic-free two-level LDS-staged binning.
// Diagnosis: same-cache-line device atomics serialize (~30ns each) — round-3's
// gcur1[64] (4 lines, 50K atomics) cost ~375us. Fix: deterministic per-(block,
// bucket) slot regions, zero global atomics on the hot path; every global store
// is a coalesced burst. Random 8B stores (45ns/line-touch) eliminated entirely.
//
//  P1: 2048 pairs/block -> stage 64 buckets (128 rows, cap 128, LDS 64KB)
//      -> flush to region1[bucket][block][128] + cnts1[block][bucket].
//  P2: bucket -> 64 subgroups (2 rows). 16 blocks/bucket, fixed slice sets,
//      stage (cap 96, LDS 48KB) -> region2[sub][p2blk][96] + cnts2.
//  P3: per 2-row band: zero 64KB LDS -> scatter entries (key&16383) -> diag ->
//      stream 64KB out coalesced. 2 blocks/CU.
// entry = uint2{ key=(row<<13)|col, f32 bits of val*scale }.
// Overflow (statistically never: cap=128 vs lambda=64) -> padded global cursor,
// consumed by filter scans; correctness never depends on "never".

#define P1_PAIRS 2048
#define NB1      64
#define CAP1     128
#define P2B      16
#define NSG      4096
#define CAP2     96
#define OVFCAP   65536

// ---------------------------------------------------------------- fused path

__global__ __launch_bounds__(64) void zero_hdr_kernel(int* __restrict__ hdr)
{
    if (threadIdx.x == 0) { hdr[0] = 0; hdr[16] = 0; }   // ovf1 cnt, ovf2 cnt (64B apart)
}

__global__ __launch_bounds__(256) void p1_kernel(
    const int*   __restrict__ idx,
    const float* __restrict__ vals,
    float scale, int m, int nblk,
    uint2* __restrict__ region1,      // [NB1][nblk][CAP1]
    int*   __restrict__ cnts1,        // [nblk][NB1]
    uint2* __restrict__ ovf1,
    int*   __restrict__ hdr)          // hdr[0] = ovf1 cursor
{
    __shared__ uint2 stage[NB1][CAP1];    // 64 KiB
    __shared__ int   cnt[NB1];
    for (int b = threadIdx.x; b < NB1; b += 256) cnt[b] = 0;
    __syncthreads();

    const int blk  = blockIdx.x;
    const int base = blk * P1_PAIRS;
#pragma unroll
    for (int it = 0; it < P1_PAIRS / 256; ++it) {
        int k = base + it * 256 + threadIdx.x;
        if (k < m) {
            int i = idx[k];
            int j = idx[m + k];
            unsigned vb = __float_as_uint(vals[k] * scale);

            unsigned key1 = ((unsigned)i << 13) | (unsigned)j;
            int b1 = i >> 7;
            int p = atomicAdd(&cnt[b1], 1);
            if (p < CAP1) stage[b1][p] = make_uint2(key1, vb);
            else { int q = atomicAdd(hdr, 1); if (q < OVFCAP) ovf1[q] = make_uint2(key1, vb); }

            unsigned key2 = ((unsigned)j << 13) | (unsigned)i;
            int b2 = j >> 7;
            p = atomicAdd(&cnt[b2], 1);
            if (p < CAP1) stage[b2][p] = make_uint2(key2, vb);
            else { int q = atomicAdd(hdr, 1); if (q < OVFCAP) ovf1[q] = make_uint2(key2, vb); }
        }
    }
    __syncthreads();

    const int wave = threadIdx.x >> 6, lane = threadIdx.x & 63;
    for (int b = wave; b < NB1; b += 4) {
        int c = cnt[b]; if (c > CAP1) c = CAP1;
        long long rb = ((long long)b * nblk + blk) * CAP1;
        for (int e = lane; e < c; e += 64) region1[rb + e] = stage[b][e];
        if (lane == 0) cnts1[blk * NB1 + b] = c;
    }
}

__global__ __launch_bounds__(256) void p2_kernel(
    const uint2* __restrict__ region1,
    const int*   __restrict__ cnts1,
    int nblk,
    uint2* __restrict__ region2,      // [NSG][P2B][CAP2]
    int*   __restrict__ cnts2,        // [NSG][P2B]
    const uint2* __restrict__ ovf1,
    const int*   __restrict__ hdr,    // hdr[0]=ovf1 cnt, hdr[16]=ovf2 cursor
    uint2* __restrict__ ovf2,
    int*   __restrict__ hdr2)
{
    __shared__ uint2 stage[64][CAP2];     // 48 KiB
    __shared__ int   cnt[64];
    const int g  = blockIdx.x >> 4;       // bucket
    const int tb = blockIdx.x & 15;
    for (int b = threadIdx.x; b < 64; b += 256) cnt[b] = 0;
    __syncthreads();

    for (int blk = tb; blk < nblk; blk += P2B) {
        int c = cnts1[blk * NB1 + g];
        long long rb = ((long long)g * nblk + blk) * CAP1;
        for (int e = threadIdx.x; e < c; e += 256) {
            uint2 en = region1[rb + e];
            int sub = (en.x >> 14) & 63;          // (row>>1)&63
            int p = atomicAdd(&cnt[sub], 1);
            if (p < CAP2) stage[sub][p] = en;
            else { int q = atomicAdd(hdr2 + 16, 1); if (q < OVFCAP) ovf2[q] = en; }
        }
    }
    if (tb == 0) {                               // rare: P1 overflow spill
        int n = hdr[0]; if (n > OVFCAP) n = OVFCAP;
        for (int e = threadIdx.x; e < n; e += 256) {
            uint2 en = ovf1[e];
            if ((int)(en.x >> 20) == g) {        // row>>7 == bucket
                int sub = (en.x >> 14) & 63;
                int p = atomicAdd(&cnt[sub], 1);
                if (p < CAP2) stage[sub][p] = en;
                else { int q = atomicAdd(hdr2 + 16, 1); if (q < OVFCAP) ovf2[q] = en; }
            }
        }
    }
    __syncthreads();

    const int wave = threadIdx.x >> 6, lane = threadIdx.x & 63;
    for (int s = wave; s < 64; s += 4) {
        int c = cnt[s]; if (c > CAP2) c = CAP2;
        int sg = (g << 6) | s;
        long long rb = ((long long)sg * P2B + tb) * CAP2;
        for (int e = lane; e < c; e += 64) region2[rb + e] = stage[s][e];
        if (lane == 0) cnts2[sg * P2B + tb] = c;
    }
}

__global__ __launch_bounds__(512) void p3_kernel(
    float* __restrict__ out,
    const float* __restrict__ h_local,
    const uint2* __restrict__ region2,
    const int*   __restrict__ cnts2,
    const uint2* __restrict__ ovf2,
    const int*   __restrict__ hdr2)
{
    __shared__ float srow[2 * 8192];              // 64 KiB: 2 rows
    float4* s4 = reinterpret_cast<float4*>(srow);
    const int s  = blockIdx.x;                    // subgroup = row>>1
    const int r0 = s << 1;

    for (int c = threadIdx.x; c < 4096; c += 512)
        s4[c] = make_float4(0.f, 0.f, 0.f, 0.f);
    __syncthreads();

    const int wave = threadIdx.x >> 6, lane = threadIdx.x & 63;
    for (int t = wave; t < P2B; t += 8) {
        int c = cnts2[s * P2B + t]; if (c > CAP2) c = CAP2;
        long long rb = ((long long)s * P2B + t) * CAP2;
        for (int e = lane; e < c; e += 64) {
            uint2 en = region2[rb + e];
            srow[en.x & 16383] = __uint_as_float(en.y);
        }
    }
    int n = hdr2[16]; if (n > OVFCAP) n = OVFCAP; // rare: P2 overflow spill
    for (int e = threadIdx.x; e < n; e += 512) {
        uint2 en = ovf2[e];
        if ((int)(en.x >> 14) == s) srow[en.x & 16383] = __uint_as_float(en.y);
    }
    if (threadIdx.x < 2) {
        int r = r0 + threadIdx.x;
        srow[((unsigned)threadIdx.x << 13) | r] = h_local[r];
    }
    __syncthreads();

    float4* orow = reinterpret_cast<float4*>(out + ((long long)r0 << 13));
    for (int c = threadIdx.x; c < 4096; c += 512)
        orow[c] = s4[c];
}

// ---------------------------------------------------------------- fallbacks

__global__ __launch_bounds__(256) void init_counts_kernel(
    float* __restrict__ out, int d, int logd)
{
    int r = blockIdx.x * blockDim.x + threadIdx.x;
    if (r < d) reinterpret_cast<int*>(out)[(long long)r << logd] = 0;
}

__global__ __launch_bounds__(256) void bin_kernel(
    float* __restrict__ out,
    const int*   __restrict__ idx,
    const float* __restrict__ vals,
    float scale, int m, int logd, int cap)
{
    int k = blockIdx.x * blockDim.x + threadIdx.x;
    if (k >= m) return;
    int i = idx[k];
    int j = idx[m + k];
    unsigned vb = __float_as_uint(vals[k] * scale);
    int* cnt_i = reinterpret_cast<int*>(out) + ((long long)i << logd);
    int* cnt_j = reinterpret_cast<int*>(out) + ((long long)j << logd);
    int p1 = atomicAdd(cnt_i, 1);
    if (p1 < cap)
        *reinterpret_cast<uint2*>(out + ((long long)i << logd) + 2 + 2 * p1) =
            make_uint2((unsigned)j, vb);
    int p2 = atomicAdd(cnt_j, 1);
    if (p2 < cap)
        *reinterpret_cast<uint2*>(out + ((long long)j << logd) + 2 + 2 * p2) =
            make_uint2((unsigned)i, vb);
}

__global__ __launch_bounds__(256) void rows_kernel(
    float* __restrict__ out,
    const float* __restrict__ h_local,
    int logd, int cap)
{
    __shared__ float srow[8192];
    const int d  = 1 << logd;
    const int n4 = d >> 2;
    float4* s4 = reinterpret_cast<float4*>(srow);
    const int r = blockIdx.x;
    float* grow = out + ((long long)r << logd);
    const float4 z = make_float4(0.f, 0.f, 0.f, 0.f);
    for (int c = threadIdx.x; c < n4; c += blockDim.x) s4[c] = z;
    __syncthreads();
    int cnt = reinterpret_cast<const int*>(grow)[0];
    if (cnt > cap) cnt = cap;
    const uint2* eb = reinterpret_cast<const uint2*>(grow + 2);
    for (int e = threadIdx.x; e < cnt; e += blockDim.x) {
        uint2 p = eb[e];
        srow[p.x] = __uint_as_float(p.y);
    }
    if (threadIdx.x == 0) srow[r] = h_local[r];
    __syncthreads();
    for (int c = threadIdx.x; c < n4; c += blockDim.x)
        reinterpret_cast<float4*>(grow)[c] = s4[c];
}

__global__ __launch_bounds__(256) void fill_diag_kernel(
    float* __restrict__ out, const float* __restrict__ h_local,
    int d, long long n)
{
    long long t = (long long)blockIdx.x * blockDim.x + threadIdx.x;
    if (t >= n) return;
    long long row = t / d;
    long long col = t - row * d;
    out[t] = (row == col) ? h_local[row] : 0.f;
}

__global__ __launch_bounds__(256) void scatter_kernel(
    float* __restrict__ out,
    const int* __restrict__ idx,
    const float* __restrict__ vals,
    float scale, int m, int d)
{
    int k = blockIdx.x * blockDim.x + threadIdx.x;
    if (k >= m) return;
    int i = idx[k];
    int j = idx[m + k];
    float v = vals[k] * scale;
    out[(long long)i * d + j] = v;
    out[(long long)j * d + i] = v;
}

// ---------------------------------------------------------------- launch

extern "C" void kernel_launch(void* const* d_in, const int* in_sizes, int n_in,
                              void* d_out, int out_size, void* d_ws, size_t ws_size,
                              hipStream_t stream) {
    const float* h_local = (const float*)d_in[0];
    const float* V_int   = (const float*)d_in[1];
    const int*   idx     = (const int*)d_in[2];

    const int d = in_sizes[0];            // 8192
    const int m = in_sizes[1];            // 1,600,000

    int logd = 0;
    while ((1 << logd) < d) ++logd;
    const bool pow2 = ((1 << logd) == d);

    const float iscale = (float)(1.0 - 0.2 / sqrt(log((double)d)));
    float* out = (float*)d_out;
    const int block = 256;

    const int nblk = (m + P1_PAIRS - 1) / P1_PAIRS;      // 782

    // ws layout (bytes, 64B-aligned blocks):
    const size_t off_hdr   = 0;                                   // 128 B
    const size_t off_ovf1  = 4096;                                // 512 KB
    const size_t off_ovf2  = off_ovf1 + (size_t)OVFCAP * 8;
    const size_t off_cnts1 = off_ovf2 + (size_t)OVFCAP * 8;
    const size_t off_cnts2 = off_cnts1 + ((size_t)nblk * NB1 * 4 + 63 & ~(size_t)63);
    const size_t off_r1    = off_cnts2 + ((size_t)NSG * P2B * 4 + 63 & ~(size_t)63);
    const size_t off_r2    = off_r1 + (size_t)NB1 * nblk * CAP1 * 8;
    const size_t ws_need   = off_r2 + (size_t)NSG * P2B * CAP2 * 8;

    const bool path4 = (d == 8192) && (m > 0) && (m <= 1900000) &&
                       (d_ws != nullptr) && (ws_size >= ws_need);

    if (path4) {
        char* ws = (char*)d_ws;
        int*   hdr     = (int*)(ws + off_hdr);
        uint2* ovf1    = (uint2*)(ws + off_ovf1);
        uint2* ovf2    = (uint2*)(ws + off_ovf2);
        int*   cnts1   = (int*)(ws + off_cnts1);
        int*   cnts2   = (int*)(ws + off_cnts2);
        uint2* region1 = (uint2*)(ws + off_r1);
        uint2* region2 = (uint2*)(ws + off_r2);

        zero_hdr_kernel<<<1, 64, 0, stream>>>(hdr);
        p1_kernel<<<nblk, block, 0, stream>>>(idx, V_int, iscale, m, nblk,
                                              region1, cnts1, ovf1, hdr);
        p2_kernel<<<NB1 * P2B, block, 0, stream>>>(region1, cnts1, nblk,
                                                   region2, cnts2, ovf1, hdr,
                                                   ovf2, hdr);
        p3_kernel<<<NSG, 512, 0, stream>>>(out, h_local, region2, cnts2, ovf2, hdr);
    } else if (pow2 && d >= 1024 && d <= 8192 &&
               ((long long)m * 2 / d) < (long long)((d - 2) / 2) / 2) {
        const int cap = (d - 2) / 2;
        init_counts_kernel<<<(d + block - 1) / block, block, 0, stream>>>(out, d, logd);
        bin_kernel<<<(m + block - 1) / block, block, 0, stream>>>(out, idx, V_int,
                                                                  iscale, m, logd, cap);
        rows_kernel<<<d, block, 0, stream>>>(out, h_local, logd, cap);
    } else {
        const long long n = (long long)d * d;
        const long long grid_fill = (n + block - 1) / block;
        fill_diag_kernel<<<(dim3)(unsigned)grid_fill, block, 0, stream>>>(out, h_local, d, n);
        const int grid_sc = (m + block - 1) / block;
        scatter_kernel<<<grid_sc, block, 0, stream>>>(out, idx, V_int, iscale, m, d);
    }
}

// Round 5
// 370.644 us; speedup vs baseline: 1.9658x; 1.0476x over previous
//
#include <hip/hip_runtime.h>
#include <math.h>

// Round 5: 2-phase streaming binning.
// R4 post-mortem: our work ~210us vs 65us traffic model. Culprits: 3-phase moves
// the entry set through HBM twice, P2 slice loop is scalar/lane-starved, cnts
// arrays force scattered accesses. New structure:
//  P1: bin pairs into 512 buckets (16 rows), LDS stage cap 16, SENTINEL-padded
//      fixed 128B slots -> region1[bucket][block][16]. No counts. Full-line
//      aligned bursts only. Overflow (~1500 entries expected) -> global list.
//  P2: one block per 4-row band: bucket slice is one contiguous 100KB stream ->
//      coalesced uint4 gather, filter (key>>15)==band, scatter into 128KiB LDS,
//      diag, stream out coalesced. Output written exactly once.
// entry = uint2{ key=(row<<13)|col, f32 bits of val*scale }, SENT key = all-ones.

#define P1_PAIRS 2048
#define NBKT     512
#define BCAP     16
#define SENTK    0xFFFFFFFFu
#define OVFCAP   65536

// ---------------------------------------------------------------- fused path

__global__ __launch_bounds__(64) void zero_hdr_kernel(int* __restrict__ hdr)
{
    if (threadIdx.x == 0) hdr[0] = 0;
}

__global__ __launch_bounds__(512) void p1_kernel(
    const int*   __restrict__ idx,     // [2, M]
    const float* __restrict__ vals,    // [M]
    float scale, int m, int nblk,
    uint2* __restrict__ region1,       // [NBKT][nblk][BCAP]
    uint2* __restrict__ ovf,
    int*   __restrict__ hdr)
{
    __shared__ uint2 stage[NBKT][BCAP];    // 64 KiB
    __shared__ int   cnt[NBKT];

    for (int f = threadIdx.x; f < NBKT * BCAP; f += 512)
        stage[f >> 4][f & 15] = make_uint2(SENTK, 0u);
    for (int b = threadIdx.x; b < NBKT; b += 512) cnt[b] = 0;
    __syncthreads();

    const int blk  = blockIdx.x;
    const int base = blk * P1_PAIRS;
#pragma unroll
    for (int it = 0; it < P1_PAIRS / 512; ++it) {
        int k = base + it * 512 + threadIdx.x;
        if (k < m) {
            int i = idx[k];
            int j = idx[m + k];
            unsigned vb = __float_as_uint(vals[k] * scale);

            unsigned k1 = ((unsigned)i << 13) | (unsigned)j;
            int b1 = i >> 4;
            int p = atomicAdd(&cnt[b1], 1);
            if (p < BCAP) stage[b1][p] = make_uint2(k1, vb);
            else { int q = atomicAdd(hdr, 1); if (q < OVFCAP) ovf[q] = make_uint2(k1, vb); }

            unsigned k2 = ((unsigned)j << 13) | (unsigned)i;
            int b2 = j >> 4;
            p = atomicAdd(&cnt[b2], 1);
            if (p < BCAP) stage[b2][p] = make_uint2(k2, vb);
            else { int q = atomicAdd(hdr, 1); if (q < OVFCAP) ovf[q] = make_uint2(k2, vb); }
        }
    }
    __syncthreads();

    // flush ALL slots (sentinel-padded): fixed 128B aligned bursts, no counts
    for (int f = threadIdx.x; f < NBKT * BCAP; f += 512) {
        int b = f >> 4, e = f & 15;
        region1[((long long)b * nblk + blk) * BCAP + e] = stage[b][e];
    }
}

__global__ __launch_bounds__(512) void p2_kernel(
    float* __restrict__ out,
    const float* __restrict__ h_local,
    const uint2* __restrict__ region1,
    int nblk,
    const uint2* __restrict__ ovf,
    const int*   __restrict__ hdr)
{
    __shared__ float srow[4 * 8192];               // 128 KiB: 4 rows
    float4* s4 = reinterpret_cast<float4*>(srow);
    const int band = blockIdx.x;                   // rows 4*band .. 4*band+3
    const int g    = band >> 2;                    // 16-row bucket

    for (int c = threadIdx.x; c < 8192; c += 512)
        s4[c] = make_float4(0.f, 0.f, 0.f, 0.f);
    __syncthreads();

    // contiguous coalesced stream over the bucket's region (2 entries / lane)
    const uint4* src = reinterpret_cast<const uint4*>(
        region1 + (long long)g * nblk * BCAP);
    const int n2 = (nblk * BCAP) >> 1;
    const unsigned bandu = (unsigned)band;
    for (int e = threadIdx.x; e < n2; e += 512) {
        uint4 en = src[e];
        if ((en.x >> 15) == bandu) srow[en.x & 0x7FFF] = __uint_as_float(en.y);
        if ((en.z >> 15) == bandu) srow[en.z & 0x7FFF] = __uint_as_float(en.w);
    }
    // rare overflow spill (L2-resident, ~1500 entries expected)
    int n = hdr[0]; if (n > OVFCAP) n = OVFCAP;
    for (int e = threadIdx.x; e < n; e += 512) {
        uint2 en = ovf[e];
        if ((en.x >> 15) == bandu) srow[en.x & 0x7FFF] = __uint_as_float(en.y);
    }
    if (threadIdx.x < 4) {
        int r = (band << 2) + threadIdx.x;
        srow[((unsigned)threadIdx.x << 13) | (unsigned)r] = h_local[r];
    }
    __syncthreads();

    float4* orow = reinterpret_cast<float4*>(out + ((long long)band << 15));
    for (int c = threadIdx.x; c < 8192; c += 512)
        orow[c] = s4[c];
}

// ---------------------------------------------------------------- fallbacks

__global__ __launch_bounds__(256) void init_counts_kernel(
    float* __restrict__ out, int d, int logd)
{
    int r = blockIdx.x * blockDim.x + threadIdx.x;
    if (r < d) reinterpret_cast<int*>(out)[(long long)r << logd] = 0;
}

__global__ __launch_bounds__(256) void bin_kernel(
    float* __restrict__ out,
    const int*   __restrict__ idx,
    const float* __restrict__ vals,
    float scale, int m, int logd, int cap)
{
    int k = blockIdx.x * blockDim.x + threadIdx.x;
    if (k >= m) return;
    int i = idx[k];
    int j = idx[m + k];
    unsigned vb = __float_as_uint(vals[k] * scale);
    int* cnt_i = reinterpret_cast<int*>(out) + ((long long)i << logd);
    int* cnt_j = reinterpret_cast<int*>(out) + ((long long)j << logd);
    int p1 = atomicAdd(cnt_i, 1);
    if (p1 < cap)
        *reinterpret_cast<uint2*>(out + ((long long)i << logd) + 2 + 2 * p1) =
            make_uint2((unsigned)j, vb);
    int p2 = atomicAdd(cnt_j, 1);
    if (p2 < cap)
        *reinterpret_cast<uint2*>(out + ((long long)j << logd) + 2 + 2 * p2) =
            make_uint2((unsigned)i, vb);
}

__global__ __launch_bounds__(256) void rows_kernel(
    float* __restrict__ out,
    const float* __restrict__ h_local,
    int logd, int cap)
{
    __shared__ float srow[8192];
    const int d  = 1 << logd;
    const int n4 = d >> 2;
    float4* s4 = reinterpret_cast<float4*>(srow);
    const int r = blockIdx.x;
    float* grow = out + ((long long)r << logd);
    const float4 z = make_float4(0.f, 0.f, 0.f, 0.f);
    for (int c = threadIdx.x; c < n4; c += blockDim.x) s4[c] = z;
    __syncthreads();
    int cnt = reinterpret_cast<const int*>(grow)[0];
    if (cnt > cap) cnt = cap;
    const uint2* eb = reinterpret_cast<const uint2*>(grow + 2);
    for (int e = threadIdx.x; e < cnt; e += blockDim.x) {
        uint2 p = eb[e];
        srow[p.x] = __uint_as_float(p.y);
    }
    if (threadIdx.x == 0) srow[r] = h_local[r];
    __syncthreads();
    for (int c = threadIdx.x; c < n4; c += blockDim.x)
        reinterpret_cast<float4*>(grow)[c] = s4[c];
}

__global__ __launch_bounds__(256) void fill_diag_kernel(
    float* __restrict__ out, const float* __restrict__ h_local,
    int d, long long n)
{
    long long t = (long long)blockIdx.x * blockDim.x + threadIdx.x;
    if (t >= n) return;
    long long row = t / d;
    long long col = t - row * d;
    out[t] = (row == col) ? h_local[row] : 0.f;
}

__global__ __launch_bounds__(256) void scatter_kernel(
    float* __restrict__ out,
    const int* __restrict__ idx,
    const float* __restrict__ vals,
    float scale, int m, int d)
{
    int k = blockIdx.x * blockDim.x + threadIdx.x;
    if (k >= m) return;
    int i = idx[k];
    int j = idx[m + k];
    float v = vals[k] * scale;
    out[(long long)i * d + j] = v;
    out[(long long)j * d + i] = v;
}

// ---------------------------------------------------------------- launch

extern "C" void kernel_launch(void* const* d_in, const int* in_sizes, int n_in,
                              void* d_out, int out_size, void* d_ws, size_t ws_size,
                              hipStream_t stream) {
    const float* h_local = (const float*)d_in[0];
    const float* V_int   = (const float*)d_in[1];
    const int*   idx     = (const int*)d_in[2];

    const int d = in_sizes[0];            // 8192
    const int m = in_sizes[1];            // 1,600,000

    int logd = 0;
    while ((1 << logd) < d) ++logd;
    const bool pow2 = ((1 << logd) == d);

    const float iscale = (float)(1.0 - 0.2 / sqrt(log((double)d)));
    float* out = (float*)d_out;
    const int block = 256;

    const int nblk = (m + P1_PAIRS - 1) / P1_PAIRS;      // 782 for m=1.6M

    // ws layout: [hdr 128B @0][ovf 512KB @4096][region1 @528384]
    const size_t off_ovf = 4096;
    const size_t off_r1  = off_ovf + (size_t)OVFCAP * sizeof(uint2);
    const size_t ws_need = off_r1 + (size_t)NBKT * nblk * BCAP * sizeof(uint2);

    const bool path5 = (d == 8192) && (m > 0) && (m <= 3000000) &&
                       (d_ws != nullptr) && (ws_size >= ws_need);

    if (path5) {
        char* ws = (char*)d_ws;
        int*   hdr     = (int*)ws;
        uint2* ovf     = (uint2*)(ws + off_ovf);
        uint2* region1 = (uint2*)(ws + off_r1);

        zero_hdr_kernel<<<1, 64, 0, stream>>>(hdr);
        p1_kernel<<<nblk, 512, 0, stream>>>(idx, V_int, iscale, m, nblk,
                                            region1, ovf, hdr);
        p2_kernel<<<2048, 512, 0, stream>>>(out, h_local, region1, nblk, ovf, hdr);
    } else if (pow2 && d >= 1024 && d <= 8192 &&
               ((long long)m * 2 / d) < (long long)((d - 2) / 2) / 2) {
        const int cap = (d - 2) / 2;
        init_counts_kernel<<<(d + block - 1) / block, block, 0, stream>>>(out, d, logd);
        bin_kernel<<<(m + block - 1) / block, block, 0, stream>>>(out, idx, V_int,
                                                                  iscale, m, logd, cap);
        rows_kernel<<<d, block, 0, stream>>>(out, h_local, logd, cap);
    } else {
        const long long n = (long long)d * d;
        const long long grid_fill = (n + block - 1) / block;
        fill_diag_kernel<<<(dim3)(unsigned)grid_fill, block, 0, stream>>>(out, h_local, d, n);
        const int grid_sc = (m + block - 1) / block;
        scatter_kernel<<<grid_sc, block, 0, stream>>>(out, idx, V_int, iscale, m, d);
    }
}

// Round 6
// 320.374 us; speedup vs baseline: 2.2743x; 1.1569x over previous
//
#include <hip/hip_runtime.h>
#include <math.h>

// Round 6: direct-to-band binning, zero global atomics, post-P2 overflow scatter.
// R5 leaks fixed: (a) buckets(16 rows) != P2 bands(4 rows) caused 4x read
// redundancy -> now NBKT=2048 four-row bands, bucket==P2 block; (b) global
// overflow cursor (same-line atomic serialization, the R3 killer) -> per-block
// LDS overflow buffer flushed to per-block region, fixed up AFTER P2 by a tiny
// random scatter (26K touches ~ 3us at R0's measured 45ns/touch rate).
// Slot = 8 entries = exactly one 64B line, sentinel-padded (slack is free at
// line granularity). d=8192=2^13 -> out flat index == key: out[key]=val.
//
//  P1 (391 blocks x 1024): bin 4096 pairs -> stage[2048][8] (128KiB) + cnt (8KiB)
//     + ovfst[512] (4KiB); flush slots as 64B line bursts; flush ovf per-block.
//  P2 (2048 blocks x 1024): per 4-row band: zero 128KiB LDS -> contiguous 25KB
//     uint4 gather of own slice -> scatter into LDS -> diag -> 128KiB coalesced out.
//  P3 (391 blocks): scatter overflow entries directly into out (rare path).

#define P1_PAIRS 4096
#define NBKT     2048
#define BCAP     8
#define OVB      512
#define SENTK    0xFFFFFFFFu
#define GCAP     65536

// ---------------------------------------------------------------- fused path

__global__ __launch_bounds__(64) void zero_hdr_kernel(int* __restrict__ ghdr)
{
    if (threadIdx.x == 0) ghdr[0] = 0;
}

__global__ __launch_bounds__(1024) void p1_kernel(
    const int*   __restrict__ idx,     // [2, M] int32
    const float* __restrict__ vals,    // [M]
    float scale, int m, int nblk,
    uint2* __restrict__ region1,       // [NBKT][nblk][BCAP]
    uint2* __restrict__ ovf,           // [nblk][OVB]
    int*   __restrict__ ovfc,          // [nblk]
    uint2* __restrict__ glist,         // [GCAP]  (never-path)
    int*   __restrict__ ghdr)
{
    __shared__ uint2 stage[NBKT][BCAP];    // 128 KiB
    __shared__ int   cnt[NBKT];            // 8 KiB
    __shared__ uint2 ovfst[OVB];           // 4 KiB
    __shared__ int   ovfn;

    uint2* sflat = &stage[0][0];
    for (int f = threadIdx.x; f < NBKT * BCAP; f += 1024)
        sflat[f] = make_uint2(SENTK, 0u);
    for (int b = threadIdx.x; b < NBKT; b += 1024) cnt[b] = 0;
    if (threadIdx.x == 0) ovfn = 0;
    __syncthreads();

    const int blk  = blockIdx.x;
    const int base = blk * P1_PAIRS;
#pragma unroll
    for (int it = 0; it < P1_PAIRS / 1024; ++it) {
        int k = base + it * 1024 + threadIdx.x;
        if (k < m) {
            int i = idx[k];
            int j = idx[m + k];
            unsigned vb = __float_as_uint(vals[k] * scale);

            unsigned k1 = ((unsigned)i << 13) | (unsigned)j;
            int b1 = i >> 2;
            int p = atomicAdd(&cnt[b1], 1);
            if (p < BCAP) stage[b1][p] = make_uint2(k1, vb);
            else {
                int q = atomicAdd(&ovfn, 1);
                if (q < OVB) ovfst[q] = make_uint2(k1, vb);
                else { int g = atomicAdd(ghdr, 1); if (g < GCAP) glist[g] = make_uint2(k1, vb); }
            }

            unsigned k2 = ((unsigned)j << 13) | (unsigned)i;
            int b2 = j >> 2;
            p = atomicAdd(&cnt[b2], 1);
            if (p < BCAP) stage[b2][p] = make_uint2(k2, vb);
            else {
                int q = atomicAdd(&ovfn, 1);
                if (q < OVB) ovfst[q] = make_uint2(k2, vb);
                else { int g = atomicAdd(ghdr, 1); if (g < GCAP) glist[g] = make_uint2(k2, vb); }
            }
        }
    }
    __syncthreads();

    // flush all slots: each bucket's 8 entries = one aligned 64B line
    for (int f = threadIdx.x; f < NBKT * BCAP; f += 1024) {
        int b = f >> 3, e = f & 7;
        region1[((long long)b * nblk + blk) * BCAP + e] = sflat[f];
    }
    // flush per-block LDS overflow (no atomics, per-block region)
    int n = ovfn; if (n > OVB) n = OVB;
    for (int e = threadIdx.x; e < n; e += 1024)
        ovf[(long long)blk * OVB + e] = ovfst[e];
    if (threadIdx.x == 0) ovfc[blk] = n;
}

__global__ __launch_bounds__(1024) void p2_kernel(
    float* __restrict__ out,
    const float* __restrict__ h_local,
    const uint2* __restrict__ region1,
    int nblk)
{
    __shared__ float srow[4 * 8192];               // 128 KiB: one 4-row band
    float4* s4 = reinterpret_cast<float4*>(srow);
    const int band = blockIdx.x;

    for (int c = threadIdx.x; c < 8192; c += 1024)
        s4[c] = make_float4(0.f, 0.f, 0.f, 0.f);
    __syncthreads();

    // contiguous 25KB gather of this band's slice (2 entries / uint4)
    const uint4* src = reinterpret_cast<const uint4*>(
        region1 + (long long)band * nblk * BCAP);
    const int n2 = (nblk * BCAP) >> 1;
    for (int e = threadIdx.x; e < n2; e += 1024) {
        uint4 en = src[e];
        if (en.x != SENTK) srow[en.x & 0x7FFF] = __uint_as_float(en.y);
        if (en.z != SENTK) srow[en.z & 0x7FFF] = __uint_as_float(en.w);
    }
    if (threadIdx.x < 4) {
        int r = (band << 2) + threadIdx.x;
        srow[((unsigned)threadIdx.x << 13) | (unsigned)r] = h_local[r];
    }
    __syncthreads();

    float4* orow = reinterpret_cast<float4*>(out + ((long long)band << 15));
    for (int c = threadIdx.x; c < 8192; c += 1024)
        orow[c] = s4[c];
}

__global__ __launch_bounds__(256) void ovf_scatter_kernel(
    float* __restrict__ out,
    const uint2* __restrict__ ovf,     // [nblk][OVB]
    const int*   __restrict__ ovfc,    // [nblk]
    const uint2* __restrict__ glist,
    const int*   __restrict__ ghdr)
{
    const int blk = blockIdx.x;
    int n = ovfc[blk]; if (n > OVB) n = OVB;
    for (int e = threadIdx.x; e < n; e += 256) {
        uint2 en = ovf[(long long)blk * OVB + e];
        out[en.x] = __uint_as_float(en.y);         // d=2^13: flat index == key
    }
    if (blk == 0) {                                // never-path spill
        int g = ghdr[0]; if (g > GCAP) g = GCAP;
        for (int e = threadIdx.x; e < g; e += 256) {
            uint2 en = glist[e];
            out[en.x] = __uint_as_float(en.y);
        }
    }
}

// ---------------------------------------------------------------- fallbacks

__global__ __launch_bounds__(256) void init_counts_kernel(
    float* __restrict__ out, int d, int logd)
{
    int r = blockIdx.x * blockDim.x + threadIdx.x;
    if (r < d) reinterpret_cast<int*>(out)[(long long)r << logd] = 0;
}

__global__ __launch_bounds__(256) void bin_kernel(
    float* __restrict__ out,
    const int*   __restrict__ idx,
    const float* __restrict__ vals,
    float scale, int m, int logd, int cap)
{
    int k = blockIdx.x * blockDim.x + threadIdx.x;
    if (k >= m) return;
    int i = idx[k];
    int j = idx[m + k];
    unsigned vb = __float_as_uint(vals[k] * scale);
    int* cnt_i = reinterpret_cast<int*>(out) + ((long long)i << logd);
    int* cnt_j = reinterpret_cast<int*>(out) + ((long long)j << logd);
    int p1 = atomicAdd(cnt_i, 1);
    if (p1 < cap)
        *reinterpret_cast<uint2*>(out + ((long long)i << logd) + 2 + 2 * p1) =
            make_uint2((unsigned)j, vb);
    int p2 = atomicAdd(cnt_j, 1);
    if (p2 < cap)
        *reinterpret_cast<uint2*>(out + ((long long)j << logd) + 2 + 2 * p2) =
            make_uint2((unsigned)i, vb);
}

__global__ __launch_bounds__(256) void rows_kernel(
    float* __restrict__ out,
    const float* __restrict__ h_local,
    int logd, int cap)
{
    __shared__ float srow[8192];
    const int d  = 1 << logd;
    const int n4 = d >> 2;
    float4* s4 = reinterpret_cast<float4*>(srow);
    const int r = blockIdx.x;
    float* grow = out + ((long long)r << logd);
    const float4 z = make_float4(0.f, 0.f, 0.f, 0.f);
    for (int c = threadIdx.x; c < n4; c += blockDim.x) s4[c] = z;
    __syncthreads();
    int cnt = reinterpret_cast<const int*>(grow)[0];
    if (cnt > cap) cnt = cap;
    const uint2* eb = reinterpret_cast<const uint2*>(grow + 2);
    for (int e = threadIdx.x; e < cnt; e += blockDim.x) {
        uint2 p = eb[e];
        srow[p.x] = __uint_as_float(p.y);
    }
    if (threadIdx.x == 0) srow[r] = h_local[r];
    __syncthreads();
    for (int c = threadIdx.x; c < n4; c += blockDim.x)
        reinterpret_cast<float4*>(grow)[c] = s4[c];
}

__global__ __launch_bounds__(256) void fill_diag_kernel(
    float* __restrict__ out, const float* __restrict__ h_local,
    int d, long long n)
{
    long long t = (long long)blockIdx.x * blockDim.x + threadIdx.x;
    if (t >= n) return;
    long long row = t / d;
    long long col = t - row * d;
    out[t] = (row == col) ? h_local[row] : 0.f;
}

__global__ __launch_bounds__(256) void scatter_kernel(
    float* __restrict__ out,
    const int* __restrict__ idx,
    const float* __restrict__ vals,
    float scale, int m, int d)
{
    int k = blockIdx.x * blockDim.x + threadIdx.x;
    if (k >= m) return;
    int i = idx[k];
    int j = idx[m + k];
    float v = vals[k] * scale;
    out[(long long)i * d + j] = v;
    out[(long long)j * d + i] = v;
}

// ---------------------------------------------------------------- launch

extern "C" void kernel_launch(void* const* d_in, const int* in_sizes, int n_in,
                              void* d_out, int out_size, void* d_ws, size_t ws_size,
                              hipStream_t stream) {
    const float* h_local = (const float*)d_in[0];
    const float* V_int   = (const float*)d_in[1];
    const int*   idx     = (const int*)d_in[2];

    const int d = in_sizes[0];            // 8192
    const int m = in_sizes[1];            // 1,600,000

    int logd = 0;
    while ((1 << logd) < d) ++logd;
    const bool pow2 = ((1 << logd) == d);

    const float iscale = (float)(1.0 - 0.2 / sqrt(log((double)d)));
    float* out = (float*)d_out;
    const int block = 256;

    const int nblk = (m + P1_PAIRS - 1) / P1_PAIRS;      // 391 for m=1.6M

    // ws layout (aligned): [ghdr 4KB][ovfc 4KB-round][glist 512KB][ovf][region1]
    const size_t off_ovfc  = 4096;
    const size_t off_glist = off_ovfc + (((size_t)nblk * 4 + 4095) & ~(size_t)4095);
    const size_t off_ovf   = off_glist + (size_t)GCAP * sizeof(uint2);
    const size_t off_r1    = off_ovf + (((size_t)nblk * OVB * sizeof(uint2) + 4095)
                                        & ~(size_t)4095);
    const size_t ws_need   = off_r1 + (size_t)NBKT * nblk * BCAP * sizeof(uint2);

    const bool path6 = (d == 8192) && (m > 0) && (m <= 2000000) &&
                       (d_ws != nullptr) && (ws_size >= ws_need);

    if (path6) {
        char* ws = (char*)d_ws;
        int*   ghdr    = (int*)ws;
        int*   ovfc    = (int*)(ws + off_ovfc);
        uint2* glist   = (uint2*)(ws + off_glist);
        uint2* ovf     = (uint2*)(ws + off_ovf);
        uint2* region1 = (uint2*)(ws + off_r1);

        zero_hdr_kernel<<<1, 64, 0, stream>>>(ghdr);
        p1_kernel<<<nblk, 1024, 0, stream>>>(idx, V_int, iscale, m, nblk,
                                             region1, ovf, ovfc, glist, ghdr);
        p2_kernel<<<NBKT, 1024, 0, stream>>>(out, h_local, region1, nblk);
        ovf_scatter_kernel<<<nblk, 256, 0, stream>>>(out, ovf, ovfc, glist, ghdr);
    } else if (pow2 && d >= 1024 && d <= 8192 &&
               ((long long)m * 2 / d) < (long long)((d - 2) / 2) / 2) {
        const int cap = (d - 2) / 2;
        init_counts_kernel<<<(d + block - 1) / block, block, 0, stream>>>(out, d, logd);
        bin_kernel<<<(m + block - 1) / block, block, 0, stream>>>(out, idx, V_int,
                                                                  iscale, m, logd, cap);
        rows_kernel<<<d, block, 0, stream>>>(out, h_local, logd, cap);
    } else {
        const long long n = (long long)d * d;
        const long long grid_fill = (n + block - 1) / block;
        fill_diag_kernel<<<(dim3)(unsigned)grid_fill, block, 0, stream>>>(out, h_local, d, n);
        const int grid_sc = (m + block - 1) / block;
        scatter_kernel<<<grid_sc, block, 0, stream>>>(out, idx, V_int, iscale, m, d);
    }
}